// Round 18
// baseline (665.018 us; speedup 1.0000x reference)
//
#include <hip/hip_runtime.h>
#include <hip/hip_bf16.h>

#define NE 512

// ---------------- static device buffers ----------------
__device__ __align__(16) float g_sv0[NE*64];
__device__ __align__(16) float g_sv[2][NE*256];
__device__ __align__(16) float g_pu4[NE*4];
__device__ __align__(16) float g_pd4[NE*4];
__device__ __align__(16) float g_puL[4*NE*64];       // per-layer p-means (u)
__device__ __align__(16) float g_pdL[4*NE*64];       // per-layer p-means (d)
__device__ __align__(16) float g_su0[64];
__device__ __align__(16) float g_sd0[64];
__device__ __align__(16) float g_part4[4*16*NE*64];  // per-(layer,chunk,j,c) partials
__device__ __align__(16) float g_spart[2][16*256];   // per-(rowgroup,col) s partials
__device__ __align__(16) float g_f[NE];
__device__ __align__(16) float g_hu[256*256];
__device__ __align__(16) float g_hd[256*256];
__device__ __align__(16) float g_orbu[256*256];
__device__ __align__(16) float g_orbd[256*256];
__device__ float g_logs[2];
__device__ unsigned g_ludone;                        // zeroed by k_front each launch

__device__ __forceinline__ float tanh_fast(float x) {
  float e = __expf(2.f * x);
  return 1.f - 2.f / (e + 1.f);
}

// ---------------- k_front: blocks 0..511 = pgeom(j=bid); 512..2559 = pchain --------
__global__ __launch_bounds__(256, 2) void k_front(const float* __restrict__ r,
                                                  const float* __restrict__ a,
                                                  const float* __restrict__ W0,
                                                  const float* __restrict__ b0,
                                                  const float* __restrict__ Wr,
                                                  const float* __restrict__ brs) {
  __shared__ __align__(16) float xrow[4*32*68];      // per-wave 32x68 row-major x
  __shared__ __align__(16) float wtile[4096];        // 64x64 W, block-shared
  __shared__ __align__(16) float msc[4*4*68];        // per-wave mean scratch
  __shared__ float red[4][4];                        // pgeom scratch
  int bid = blockIdx.x, t = threadIdx.x;
  if (bid == 0 && t == 0) g_ludone = 0u;             // reset completion flag
  if (bid < 512) {
    // ---- pgeom ----
    int j = bid;
    if (j == 0) {
      for (int h = 0; h < 2; ++h) {
        int e = h*256 + t;
        float rx = r[3*e], ry = r[3*e+1], rz = r[3*e+2];
        float facc = 0.f;
        #pragma unroll
        for (int at = 0; at < 16; ++at) {
          float dx = rx - a[3*at], dy = ry - a[3*at+1], dz = rz - a[3*at+2];
          float len = sqrtf(dx*dx + dy*dy + dz*dz);
          g_sv0[e*64 + 4*at + 0] = dx;
          g_sv0[e*64 + 4*at + 1] = dy;
          g_sv0[e*64 + 4*at + 2] = dz;
          g_sv0[e*64 + 4*at + 3] = len;
          facc += expf(-len);
        }
        g_f[e] = facc;
      }
      __syncthreads();
      if (t < 128) {
        int h = t >> 6, c = t & 63;
        float s = 0.f;
        for (int i = 0; i < 256; ++i) s += g_sv0[(h*256 + i)*64 + c];
        (h ? g_sd0 : g_su0)[c] = s * (1.f/256.f);
      }
      __syncthreads();
    }
    float rjx = r[3*j], rjy = r[3*j+1], rjz = r[3*j+2];
    for (int h = 0; h < 2; ++h) {
      int i = h*256 + t;
      float dx = rjx - r[3*i], dy = rjy - r[3*i+1], dz = rjz - r[3*i+2];
      float ee = (i == j) ? 1.f : 0.f;
      float ex = dx+ee, ey = dy+ee, ez = dz+ee;
      float len = sqrtf(ex*ex + ey*ey + ez*ez);
      float v0 = dx, v1 = dy, v2 = dz, v3 = len;
      #pragma unroll
      for (int m = 1; m < 64; m <<= 1) {
        v0 += __shfl_xor(v0, m); v1 += __shfl_xor(v1, m);
        v2 += __shfl_xor(v2, m); v3 += __shfl_xor(v3, m);
      }
      if ((t & 63) == 0) {
        int wv = t >> 6;
        red[wv][0]=v0; red[wv][1]=v1; red[wv][2]=v2; red[wv][3]=v3;
      }
      __syncthreads();
      if (t == 0) {
        float* dst = h ? g_pd4 : g_pu4;
        #pragma unroll
        for (int c = 0; c < 4; ++c)
          dst[j*4 + c] = (red[0][c]+red[1][c]+red[2][c]+red[3][c]) * (1.f/256.f);
      }
      __syncthreads();
    }
  } else {
    // ---- pchain: 4 layers, register-tiled, means only ----
    int lane = t & 63, wv = t >> 6;
    int gw = (bid - 512)*4 + wv;         // 0..8191
    int j = gw >> 4, chunk = gw & 15;
    int i0 = chunk * 32;
    int rg = lane >> 4, cg = lane & 15;
    float* xr = xrow + wv*(32*68);
    float* ms = msc + wv*(4*68);
    float rjx = r[3*j], rjy = r[3*j+1], rjz = r[3*j+2];
    float xres[8][4];
    {
      float4 w0 = *(const float4*)&W0[0*64 + 4*cg];
      float4 w1 = *(const float4*)&W0[1*64 + 4*cg];
      float4 w2 = *(const float4*)&W0[2*64 + 4*cg];
      float4 w3 = *(const float4*)&W0[3*64 + 4*cg];
      float4 bv = *(const float4*)&b0[4*cg];
      #pragma unroll
      for (int q = 0; q < 8; ++q) {
        int row = 4*q + rg;
        int i = i0 + row;
        float dx = rjx - r[3*i], dy = rjy - r[3*i+1], dz = rjz - r[3*i+2];
        float ee = (i == j) ? 1.f : 0.f;
        float ex = dx+ee, ey = dy+ee, ez = dz+ee;
        float len = sqrtf(ex*ex + ey*ey + ez*ez);
        float y0 = tanh_fast(bv.x + dx*w0.x + dy*w1.x + dz*w2.x + len*w3.x);
        float y1 = tanh_fast(bv.y + dx*w0.y + dy*w1.y + dz*w2.y + len*w3.y);
        float y2 = tanh_fast(bv.z + dx*w0.z + dy*w1.z + dz*w2.z + len*w3.z);
        float y3 = tanh_fast(bv.w + dx*w0.w + dy*w1.w + dz*w2.w + len*w3.w);
        xres[q][0]=y0; xres[q][1]=y1; xres[q][2]=y2; xres[q][3]=y3;
        float4 yv; yv.x=y0; yv.y=y1; yv.z=y2; yv.w=y3;
        *(float4*)&xr[row*68 + 4*cg] = yv;
      }
      float cs0=0,cs1=0,cs2=0,cs3=0;
      #pragma unroll
      for (int q=0;q<8;++q){cs0+=xres[q][0];cs1+=xres[q][1];cs2+=xres[q][2];cs3+=xres[q][3];}
      ms[rg*68+4*cg+0]=cs0; ms[rg*68+4*cg+1]=cs1;
      ms[rg*68+4*cg+2]=cs2; ms[rg*68+4*cg+3]=cs3;
      float tot = ms[0*68+lane]+ms[1*68+lane]+ms[2*68+lane]+ms[3*68+lane];
      g_part4[0*(16*NE*64) + chunk*(NE*64) + j*64 + lane] = tot;
    }
    for (int l = 0; l < 3; ++l) {
      __syncthreads();
      for (int idx = t; idx < 4096; idx += 256) wtile[idx] = Wr[l*4096 + idx];
      __syncthreads();
      float4 bv = *(const float4*)&brs[l*64 + 4*cg];
      float acc[8][4];
      #pragma unroll
      for (int q=0;q<8;++q){acc[q][0]=bv.x;acc[q][1]=bv.y;acc[q][2]=bv.z;acc[q][3]=bv.w;}
      #pragma unroll 4
      for (int kq = 0; kq < 16; ++kq) {
        float4 wv0 = *(const float4*)&wtile[(4*kq+0)*64 + 4*cg];
        float4 wv1 = *(const float4*)&wtile[(4*kq+1)*64 + 4*cg];
        float4 wv2 = *(const float4*)&wtile[(4*kq+2)*64 + 4*cg];
        float4 wv3 = *(const float4*)&wtile[(4*kq+3)*64 + 4*cg];
        #pragma unroll
        for (int q = 0; q < 8; ++q) {
          float4 xv = *(const float4*)&xr[(4*q+rg)*68 + 4*kq];
          acc[q][0] += xv.x*wv0.x + xv.y*wv1.x + xv.z*wv2.x + xv.w*wv3.x;
          acc[q][1] += xv.x*wv0.y + xv.y*wv1.y + xv.z*wv2.y + xv.w*wv3.y;
          acc[q][2] += xv.x*wv0.z + xv.y*wv1.z + xv.z*wv2.z + xv.w*wv3.z;
          acc[q][3] += xv.x*wv0.w + xv.y*wv1.w + xv.z*wv2.w + xv.w*wv3.w;
        }
      }
      float cs0=0,cs1=0,cs2=0,cs3=0;
      #pragma unroll
      for (int q = 0; q < 8; ++q) {
        float y0 = tanh_fast(acc[q][0]) + xres[q][0];
        float y1 = tanh_fast(acc[q][1]) + xres[q][1];
        float y2 = tanh_fast(acc[q][2]) + xres[q][2];
        float y3 = tanh_fast(acc[q][3]) + xres[q][3];
        xres[q][0]=y0; xres[q][1]=y1; xres[q][2]=y2; xres[q][3]=y3;
        float4 yv; yv.x=y0; yv.y=y1; yv.z=y2; yv.w=y3;
        *(float4*)&xr[(4*q+rg)*68 + 4*cg] = yv;
        cs0+=y0; cs1+=y1; cs2+=y2; cs3+=y3;
      }
      ms[rg*68+4*cg+0]=cs0; ms[rg*68+4*cg+1]=cs1;
      ms[rg*68+4*cg+2]=cs2; ms[rg*68+4*cg+3]=cs3;
      float tot = ms[0*68+lane]+ms[1*68+lane]+ms[2*68+lane]+ms[3*68+lane];
      g_part4[(l+1)*(16*NE*64) + chunk*(NE*64) + j*64 + lane] = tot;
    }
  }
}

// ---------------- s-channel matmul ----------------
// which: 0=layer0 (+ folded reduce_p), 1..3=layer l, 4=FUSED heads, 6=FUSED orbitals
// rsp: g_spart buffer to READ s-means from (-1 = use g_su0/g_sd0 or none)
// wsp: g_spart buffer to WRITE col partials to (-1 = none)
template<int PUK, int SVK, int MEANK>
__global__ __launch_bounds__(256) void k_smm(int which, const float* __restrict__ W,
                                             const float* __restrict__ Wb,
                                             const float* __restrict__ W2,
                                             const float* __restrict__ Wb2,
                                             int pl, int rsp, int wsp) {
  constexpr int MAINK = 2*PUK + SVK;
  __shared__ __align__(16) float wsl[MAINK*32];
  __shared__ float insl[32*(MAINK+1)];
  __shared__ float biasv[32];
  __shared__ float bred[256];
  __shared__ float susd[512];
  __shared__ float wred[4][8][4];
  const float *pu_p=nullptr, *pd_p=nullptr, *sv_p=nullptr, *su_p=nullptr, *sd_p=nullptr;
  const float *res_p=nullptr, *rs_p=nullptr;
  float* out_p = nullptr;
  int t = threadIdx.x;
  int rg = blockIdx.x, cg = blockIdx.y;
  // ---- folded reduce_p (smm0 dispatch only; independent of smm0's own work) ----
  if (which == 0) {
    int fid = blockIdx.y*16 + blockIdx.x;   // 0..127
    #pragma unroll
    for (int rep = 0; rep < 8; ++rep) {
      int idx = fid*2048 + rep*256 + t;     // covers 262144
      int l = idx >> 16;
      int rem = idx & 65535;
      int half = rem >> 15;
      int r2 = rem & 32767;
      const float* pp = g_part4 + l*(16*NE*64) + half*(8*NE*64) + r2;
      float s = 0.f;
      #pragma unroll
      for (int ch = 0; ch < 8; ++ch) s += pp[ch*(NE*64)];
      (half ? g_pdL : g_puL)[l*(NE*64) + r2] = s * (1.f/256.f);
    }
  }
  int grp = 0, rgl = rg;
  if (which >= 4) { grp = rg >> 3; rgl = rg & 7; }
  const float* Wsel = (which >= 4 && grp) ? W2 : W;
  const float* Wbsel = (which >= 4 && grp) ? Wb2 : Wb;
  int in_base = 0, dotanh = 1;
  switch (which) {
    case 0: pu_p=g_pu4; pd_p=g_pd4; su_p=g_su0; sd_p=g_sd0; sv_p=g_sv0;
            out_p=g_sv[0]; in_base=rg*32; break;
    case 1: case 2: case 3:
      pu_p=g_puL + pl*(NE*64); pd_p=g_pdL + pl*(NE*64);
      sv_p=g_sv[(which+1)&1]; res_p=sv_p; out_p=g_sv[which&1]; in_base=rg*32; break;
    case 4: pu_p=g_puL + pl*(NE*64); pd_p=g_pdL + pl*(NE*64);
            sv_p=g_sv[1]; out_p = grp ? g_hd : g_hu; in_base = grp*256 + rgl*32; break;
    default: sv_p = grp ? g_hd : g_hu; out_p = grp ? g_orbd : g_orbu;
             rs_p = g_f + grp*256; in_base = rgl*32; dotanh = 0; break;
  }
  // rebuild s-means from producer's col partials (replaces the smean dispatch)
  if (rsp >= 0 && MEANK == 256) {
    const float* sp = g_spart[rsp];
    for (int e = t; e < 512; e += 256) {
      int half = e >> 8, c = e & 255;
      float s = 0.f;
      #pragma unroll
      for (int g8 = 0; g8 < 8; ++g8) s += sp[(half*8 + g8)*256 + c];
      susd[e] = s * (1.f/256.f);
    }
    su_p = &susd[0]; sd_p = &susd[256];
    __syncthreads();
  }
  int out_base = (which >= 4) ? rgl*32 : rg*32;
  int col0 = cg * 32;
  for (int idx = t; idx < MAINK*32; idx += 256) {
    int c = idx >> 5, cl = idx & 31;
    wsl[idx] = Wsel[(2*MEANK + c)*256 + col0 + cl];
  }
  for (int rr = 0; rr < 32; ++rr) {
    int row = in_base + rr;
    for (int c = t; c < MAINK; c += 256) {
      float v;
      if (c < PUK) v = pu_p[row*PUK + c];
      else if (c < 2*PUK) v = pd_p[row*PUK + (c - PUK)];
      else v = sv_p[row*SVK + (c - 2*PUK)];
      insl[rr*(MAINK+1) + c] = v;
    }
  }
  {
    int pcol = t & 31, ps = t >> 5;
    float bacc = 0.f;
    if (MEANK > 0) {
      for (int c = ps; c < MEANK; c += 8)
        bacc += su_p[c]*Wsel[c*256 + col0 + pcol] + sd_p[c]*Wsel[(MEANK + c)*256 + col0 + pcol];
    }
    bred[ps*32 + pcol] = bacc;
  }
  __syncthreads();
  if (t < 32) {
    float s = Wbsel[col0 + t];
    #pragma unroll
    for (int p8 = 0; p8 < 8; ++p8) s += bred[p8*32 + t];
    biasv[t] = s;
  }
  __syncthreads();
  int c4 = t & 7, rl = t >> 3;
  float a0 = biasv[4*c4], a1 = biasv[4*c4+1], a2 = biasv[4*c4+2], a3 = biasv[4*c4+3];
  const float* inrow = &insl[rl*(MAINK+1)];
  #pragma unroll 4
  for (int c = 0; c < MAINK; ++c) {
    float iv = inrow[c];
    float4 wv = *(const float4*)&wsl[c*32 + 4*c4];
    a0 += iv*wv.x; a1 += iv*wv.y; a2 += iv*wv.z; a3 += iv*wv.w;
  }
  int rowA = out_base + rl;
  int col = col0 + 4*c4;
  if (dotanh) { a0=tanh_fast(a0); a1=tanh_fast(a1); a2=tanh_fast(a2); a3=tanh_fast(a3); }
  if (res_p) {
    float4 rv = *(const float4*)&res_p[rowA*256 + col];
    a0 += rv.x; a1 += rv.y; a2 += rv.z; a3 += rv.w;
  }
  if (rs_p) { float fsc = rs_p[rowA]; a0*=fsc; a1*=fsc; a2*=fsc; a3*=fsc; }
  float4 ov; ov.x=a0; ov.y=a1; ov.z=a2; ov.w=a3;
  *(float4*)&out_p[rowA*256 + col] = ov;
  // ---- col partials for the NEXT layer's s-means ----
  if (wsp >= 0) {
    int lane = t & 63, wv = t >> 6;
    float s0=a0, s1=a1, s2=a2, s3=a3;
    #pragma unroll
    for (int m = 8; m < 64; m <<= 1) {
      s0 += __shfl_xor(s0, m); s1 += __shfl_xor(s1, m);
      s2 += __shfl_xor(s2, m); s3 += __shfl_xor(s3, m);
    }
    if ((lane >> 3) == 0) {
      wred[wv][c4][0]=s0; wred[wv][c4][1]=s1; wred[wv][c4][2]=s2; wred[wv][c4][3]=s3;
    }
    __syncthreads();
    if (t < 32) {
      int cc4 = t >> 2, cc = t & 3;
      float tot = wred[0][cc4][cc]+wred[1][cc4][cc]+wred[2][cc4][cc]+wred[3][cc4][cc];
      g_spart[wsp][rg*256 + col0 + 4*cc4 + cc] = tot;
    }
  }
}

// ---------------- LU v10: v8 + owner-register pivot search (UNBUNDLED v9 idea) ----
// v8's structure kept exactly (update/publish/extract, one barrier); ONLY change:
// the extract group searches col k+1 in its REGISTERS (masked candidates + 5-step
// DPP key-max within its half-wave) and posts (p,piv) to LDS scalars pre-barrier.
// Post-barrier all threads read 2 broadcast scalars instead of the b128 colbuf
// read + 6-DPP + 4-readlane chain.
#define REP8(M) M(0) M(1) M(2) M(3) M(4) M(5) M(6) M(7)
#define DPPMAX(v, CTRL) { unsigned _o = (unsigned)__builtin_amdgcn_update_dpp(0, (int)(v), CTRL, 0xf, 0xf, true); \
                          (v) = (v) > _o ? (v) : _o; }

__global__ __launch_bounds__(512, 2) void k_lu(float* __restrict__ out) {
  __shared__ __align__(16) float colbuf[2][256];
  __shared__ __align__(16) float prowbuf[2][16*20];
  __shared__ unsigned scal_p[2];
  __shared__ float scal_v[2];
  const float* A = (blockIdx.x == 0) ? g_orbu : g_orbd;
  int t = threadIdx.x;
  int tile_c = t >> 5;        // 0..15 -> cols 16*tile_c .. +15 (half-wave group)
  int tile_r = t & 31;        // 0..31 -> rows 8*tile_r .. +7
  int lane = t & 63;
  int br = tile_r * 8;
  int pb = tile_c * 20;
  const float4* Ap = (const float4*)(A + br*256 + tile_c*16);
#define DECLROW(R) float4 M##R##_0 = Ap[R*64+0], M##R##_1 = Ap[R*64+1], \
                          M##R##_2 = Ap[R*64+2], M##R##_3 = Ap[R*64+3];
  REP8(DECLROW)
#undef DECLROW
  unsigned um8 = 0;           // used-mask for my 8 rows
#define CANDV(V, R) { unsigned kk = (um8 & (1u<<R)) ? 0u : ((__float_as_uint(fabsf(V)) & 0xFFFFFF00u) | (unsigned)(br + R)); \
                      if (kk > key) key = kk; }
  // ---- pre-loop: group 0 extracts + searches column 0 ----
  if (tile_c == 0) {
    float e0 = M0_0.x, e1 = M1_0.x, e2 = M2_0.x, e3 = M3_0.x;
    float e4 = M4_0.x, e5 = M5_0.x, e6 = M6_0.x, e7 = M7_0.x;
    float4 w0; w0.x=e0; w0.y=e1; w0.z=e2; w0.w=e3;
    float4 w1; w1.x=e4; w1.y=e5; w1.z=e6; w1.w=e7;
    *(float4*)&colbuf[0][br] = w0;
    *(float4*)&colbuf[0][br+4] = w1;
    unsigned key = 0;
    CANDV(e0,0) CANDV(e1,1) CANDV(e2,2) CANDV(e3,3)
    CANDV(e4,4) CANDV(e5,5) CANDV(e6,6) CANDV(e7,7)
    DPPMAX(key, 0x111) DPPMAX(key, 0x112) DPPMAX(key, 0x114) DPPMAX(key, 0x118)
    DPPMAX(key, 0x142)
    int srcl = __builtin_amdgcn_readfirstlane((lane & 32) | 31);
    int p = (int)((unsigned)__builtin_amdgcn_readlane((int)key, srcl) & 255u);
    if (tile_r == (p >> 3)) {
      float val;
      switch (p & 7) {
        case 0: val=e0; break; case 1: val=e1; break; case 2: val=e2; break;
        case 3: val=e3; break; case 4: val=e4; break; case 5: val=e5; break;
        case 6: val=e6; break; default: val=e7; break;
      }
      scal_v[0] = val;
    }
    if ((lane & 31) == 0) scal_p[0] = (unsigned)p;
  }
  __syncthreads();
  float prod = 1.f;
  int esum = 0;
  float m0=0,m1=0,m2=0,m3=0,m4=0,m5=0,m6=0,m7=0;
  for (int k = 0; k < 256; ++k) {
    int buf = k & 1;
    unsigned pk = scal_p[buf];
    float piv = scal_v[buf];
    int ee; float mant = frexpf(fabsf(piv), &ee);
    prod *= mant; esum += ee;
    int e2n; prod = frexpf(prod, &e2n); esum += e2n;
    if ((int)(pk >> 3) == tile_r) um8 |= 1u << (pk & 7);
    if (k == 255) break;
    // ---- bulk rank-1 update for pivot k-1 (v8 structure) ----
    bool aliveU = (tile_c*16 + 15) >= k;
    if (k > 0 && aliveU) {
      const float* pwp = &prowbuf[buf^1][pb];
      float4 P0 = *(const float4*)&pwp[0];
      float4 P1 = *(const float4*)&pwp[4];
      float4 P2 = *(const float4*)&pwp[8];
      float4 P3 = *(const float4*)&pwp[12];
#define UPD(R) { float mr = m##R; \
  M##R##_0.x -= mr*P0.x; M##R##_0.y -= mr*P0.y; M##R##_0.z -= mr*P0.z; M##R##_0.w -= mr*P0.w; \
  M##R##_1.x -= mr*P1.x; M##R##_1.y -= mr*P1.y; M##R##_1.z -= mr*P1.z; M##R##_1.w -= mr*P1.w; \
  M##R##_2.x -= mr*P2.x; M##R##_2.y -= mr*P2.y; M##R##_2.z -= mr*P2.z; M##R##_2.w -= mr*P2.w; \
  M##R##_3.x -= mr*P3.x; M##R##_3.y -= mr*P3.y; M##R##_3.z -= mr*P3.z; M##R##_3.w -= mr*P3.w; }
      REP8(UPD)
#undef UPD
    }
    float rp = 1.0f / piv;
    float4 ca = *(const float4*)&colbuf[buf][br];
    float4 cb2 = *(const float4*)&colbuf[buf][br+4];
    m0 = ca.x*rp; m1 = ca.y*rp; m2 = ca.z*rp; m3 = ca.w*rp;
    m4 = cb2.x*rp; m5 = cb2.y*rp; m6 = cb2.z*rp; m7 = cb2.w*rp;
    int p = (int)pk;
    bool aliveK = (tile_c*16 + 15) > k;
    // ---- publish pivot row k (post-UPD registers) ----
    if (aliveK && tile_r == (p >> 3)) {
      float* pw_ = &prowbuf[buf][pb];
      switch (p & 7) {
#define PUBC(R) case R: *(float4*)&pw_[0] = M##R##_0; *(float4*)&pw_[4] = M##R##_1; \
                        *(float4*)&pw_[8] = M##R##_2; *(float4*)&pw_[12] = M##R##_3; break;
        REP8(PUBC)
#undef PUBC
      }
    }
    // ---- extract col k+1 + inline col-k update + SEARCH in registers ----
    int kn = k + 1;
    if (tile_c == (kn >> 4)) {
      float e0,e1,e2b,e3,e4,e5,e6,e7;
      switch (kn & 15) {
#define EXTC(I, G, C) case I: e0=M0_##G.C; e1=M1_##G.C; e2b=M2_##G.C; e3=M3_##G.C; \
                              e4=M4_##G.C; e5=M5_##G.C; e6=M6_##G.C; e7=M7_##G.C; break;
        EXTC(0,0,x) EXTC(1,0,y) EXTC(2,0,z) EXTC(3,0,w)
        EXTC(4,1,x) EXTC(5,1,y) EXTC(6,1,z) EXTC(7,1,w)
        EXTC(8,2,x) EXTC(9,2,y) EXTC(10,2,z) EXTC(11,2,w)
        EXTC(12,3,x) EXTC(13,3,y) EXTC(14,3,z) EXTC(15,3,w)
#undef EXTC
      }
      float sel;
      switch (p & 7) {
        case 0: sel = e0; break; case 1: sel = e1; break;
        case 2: sel = e2b; break; case 3: sel = e3; break;
        case 4: sel = e4; break; case 5: sel = e5; break;
        case 6: sel = e6; break; default: sel = e7; break;
      }
      float pv = __shfl(sel, (tile_c & 1)*32 + (p >> 3), 64);
      float w0x = e0 - m0*pv, w0y = e1 - m1*pv, w0z = e2b - m2*pv, w0w = e3 - m3*pv;
      float w1x = e4 - m4*pv, w1y = e5 - m5*pv, w1z = e6 - m6*pv, w1w = e7 - m7*pv;
      float4 w0; w0.x=w0x; w0.y=w0y; w0.z=w0z; w0.w=w0w;
      float4 w1; w1.x=w1x; w1.y=w1y; w1.z=w1z; w1.w=w1w;
      *(float4*)&colbuf[buf^1][br]   = w0;
      *(float4*)&colbuf[buf^1][br+4] = w1;
      // search col k+1 within this half-wave (um8 already includes pivot k)
      unsigned key = 0;
      CANDV(w0x,0) CANDV(w0y,1) CANDV(w0z,2) CANDV(w0w,3)
      CANDV(w1x,4) CANDV(w1y,5) CANDV(w1z,6) CANDV(w1w,7)
      DPPMAX(key, 0x111) DPPMAX(key, 0x112) DPPMAX(key, 0x114) DPPMAX(key, 0x118)
      DPPMAX(key, 0x142)
      int srcl = __builtin_amdgcn_readfirstlane((lane & 32) | 31);
      int pn = (int)((unsigned)__builtin_amdgcn_readlane((int)key, srcl) & 255u);
      if (tile_r == (pn >> 3)) {
        float val;
        switch (pn & 7) {
          case 0: val=w0x; break; case 1: val=w0y; break; case 2: val=w0z; break;
          case 3: val=w0w; break; case 4: val=w1x; break; case 5: val=w1y; break;
          case 6: val=w1z; break; default: val=w1w; break;
        }
        scal_v[buf^1] = val;
      }
      if ((lane & 31) == 0) scal_p[buf^1] = (unsigned)pn;
    }
    __syncthreads();
  }
#undef CANDV
  if (t == 0) {
    float ls = logf(prod) + (float)esum * 0.69314718055994531f;
    __hip_atomic_store(&g_logs[blockIdx.x], ls, __ATOMIC_RELEASE, __HIP_MEMORY_SCOPE_AGENT);
    unsigned old = __hip_atomic_fetch_add(&g_ludone, 1u, __ATOMIC_ACQ_REL, __HIP_MEMORY_SCOPE_AGENT);
    if (old == 1u) {
      float l0 = __hip_atomic_load(&g_logs[0], __ATOMIC_ACQUIRE, __HIP_MEMORY_SCOPE_AGENT);
      float l1 = __hip_atomic_load(&g_logs[1], __ATOMIC_ACQUIRE, __HIP_MEMORY_SCOPE_AGENT);
      out[0] = l0 + l1;
    }
  }
}

// ---------------- launch (8 dispatches) ----------------
extern "C" void kernel_launch(void* const* d_in, const int* in_sizes, int n_in,
                              void* d_out, int out_size, void* d_ws, size_t ws_size,
                              hipStream_t stream) {
  const float* r     = (const float*)d_in[0];
  const float* a     = (const float*)d_in[1];
  const float* V0_W  = (const float*)d_in[2];
  const float* V0_b  = (const float*)d_in[3];
  const float* Vr_W  = (const float*)d_in[4];
  const float* Vr_b  = (const float*)d_in[5];
  const float* W0_W  = (const float*)d_in[6];
  const float* W0_b  = (const float*)d_in[7];
  const float* Wr_W  = (const float*)d_in[8];
  const float* Wr_b  = (const float*)d_in[9];
  const float* Vhu_W = (const float*)d_in[10];
  const float* Vhu_b = (const float*)d_in[11];
  const float* Vhd_W = (const float*)d_in[12];
  const float* Vhd_b = (const float*)d_in[13];
  const float* wu_W  = (const float*)d_in[14];
  const float* wu_b  = (const float*)d_in[15];
  const float* wd_W  = (const float*)d_in[16];
  const float* wd_b  = (const float*)d_in[17];
  float* out = (float*)d_out;

  k_front<<<2560, 256, 0, stream>>>(r, a, W0_W, W0_b, Wr_W, Wr_b);
  // smm0 carries the folded reduce_p
  k_smm<4,64,64><<<dim3(16,8), 256, 0, stream>>>(0, V0_W, V0_b, nullptr, nullptr,
                                                 0, -1, 0);
  k_smm<64,256,256><<<dim3(16,8), 256, 0, stream>>>(1, Vr_W + 0*896*256, Vr_b + 0,
                                                    nullptr, nullptr, 0, 0, 1);
  k_smm<64,256,256><<<dim3(16,8), 256, 0, stream>>>(2, Vr_W + 1*896*256, Vr_b + 256,
                                                    nullptr, nullptr, 1, 1, 0);
  k_smm<64,256,256><<<dim3(16,8), 256, 0, stream>>>(3, Vr_W + 2*896*256, Vr_b + 512,
                                                    nullptr, nullptr, 2, 0, 1);
  k_smm<64,256,256><<<dim3(16,8), 256, 0, stream>>>(4, Vhu_W, Vhu_b, Vhd_W, Vhd_b,
                                                    3, 1, -1);
  k_smm<0,256,0><<<dim3(16,8), 256, 0, stream>>>(6, wu_W, wu_b, wd_W, wd_b,
                                                 0, -1, -1);
  k_lu<<<2, 512, 0, stream>>>(out);
}

// Round 19
// 609.927 us; speedup vs baseline: 1.0903x; 1.0903x over previous
//
#include <hip/hip_runtime.h>
#include <hip/hip_bf16.h>

#define NE 512

// ---------------- static device buffers ----------------
__device__ __align__(16) float g_sv0[NE*64];
__device__ __align__(16) float g_sv[2][NE*256];
__device__ __align__(16) float g_pu4[NE*4];
__device__ __align__(16) float g_pd4[NE*4];
__device__ __align__(16) float g_puL[4*NE*64];       // per-layer p-means (u)
__device__ __align__(16) float g_pdL[4*NE*64];       // per-layer p-means (d)
__device__ __align__(16) float g_su0[64];
__device__ __align__(16) float g_sd0[64];
__device__ __align__(16) float g_part4[4*16*NE*64];  // per-(layer,chunk,j,c) partials
__device__ __align__(16) float g_spart[2][16*256];   // per-(rowgroup,col) s partials
__device__ __align__(16) float g_f[NE];
__device__ __align__(16) float g_hu[256*256];
__device__ __align__(16) float g_hd[256*256];
__device__ __align__(16) float g_orbu[256*256];
__device__ __align__(16) float g_orbd[256*256];
__device__ float g_logs[2];
__device__ unsigned g_ludone;                        // zeroed by k_front each launch

__device__ __forceinline__ float tanh_fast(float x) {
  float e = __expf(2.f * x);
  return 1.f - 2.f / (e + 1.f);
}

// ---------------- k_front: blocks 0..511 = pgeom(j=bid); 512..2559 = pchain --------
__global__ __launch_bounds__(256, 2) void k_front(const float* __restrict__ r,
                                                  const float* __restrict__ a,
                                                  const float* __restrict__ W0,
                                                  const float* __restrict__ b0,
                                                  const float* __restrict__ Wr,
                                                  const float* __restrict__ brs) {
  __shared__ __align__(16) float xrow[4*32*68];      // per-wave 32x68 row-major x
  __shared__ __align__(16) float wtile[4096];        // 64x64 W, block-shared
  __shared__ __align__(16) float msc[4*4*68];        // per-wave mean scratch
  __shared__ float red[4][4];                        // pgeom scratch
  int bid = blockIdx.x, t = threadIdx.x;
  if (bid == 0 && t == 0) g_ludone = 0u;             // reset completion flag
  if (bid < 512) {
    // ---- pgeom ----
    int j = bid;
    if (j == 0) {
      for (int h = 0; h < 2; ++h) {
        int e = h*256 + t;
        float rx = r[3*e], ry = r[3*e+1], rz = r[3*e+2];
        float facc = 0.f;
        #pragma unroll
        for (int at = 0; at < 16; ++at) {
          float dx = rx - a[3*at], dy = ry - a[3*at+1], dz = rz - a[3*at+2];
          float len = sqrtf(dx*dx + dy*dy + dz*dz);
          g_sv0[e*64 + 4*at + 0] = dx;
          g_sv0[e*64 + 4*at + 1] = dy;
          g_sv0[e*64 + 4*at + 2] = dz;
          g_sv0[e*64 + 4*at + 3] = len;
          facc += expf(-len);
        }
        g_f[e] = facc;
      }
      __syncthreads();
      if (t < 128) {
        int h = t >> 6, c = t & 63;
        float s = 0.f;
        for (int i = 0; i < 256; ++i) s += g_sv0[(h*256 + i)*64 + c];
        (h ? g_sd0 : g_su0)[c] = s * (1.f/256.f);
      }
      __syncthreads();
    }
    float rjx = r[3*j], rjy = r[3*j+1], rjz = r[3*j+2];
    for (int h = 0; h < 2; ++h) {
      int i = h*256 + t;
      float dx = rjx - r[3*i], dy = rjy - r[3*i+1], dz = rjz - r[3*i+2];
      float ee = (i == j) ? 1.f : 0.f;
      float ex = dx+ee, ey = dy+ee, ez = dz+ee;
      float len = sqrtf(ex*ex + ey*ey + ez*ez);
      float v0 = dx, v1 = dy, v2 = dz, v3 = len;
      #pragma unroll
      for (int m = 1; m < 64; m <<= 1) {
        v0 += __shfl_xor(v0, m); v1 += __shfl_xor(v1, m);
        v2 += __shfl_xor(v2, m); v3 += __shfl_xor(v3, m);
      }
      if ((t & 63) == 0) {
        int wv = t >> 6;
        red[wv][0]=v0; red[wv][1]=v1; red[wv][2]=v2; red[wv][3]=v3;
      }
      __syncthreads();
      if (t == 0) {
        float* dst = h ? g_pd4 : g_pu4;
        #pragma unroll
        for (int c = 0; c < 4; ++c)
          dst[j*4 + c] = (red[0][c]+red[1][c]+red[2][c]+red[3][c]) * (1.f/256.f);
      }
      __syncthreads();
    }
  } else {
    // ---- pchain: 4 layers, register-tiled, means only ----
    int lane = t & 63, wv = t >> 6;
    int gw = (bid - 512)*4 + wv;         // 0..8191
    int j = gw >> 4, chunk = gw & 15;
    int i0 = chunk * 32;
    int rg = lane >> 4, cg = lane & 15;
    float* xr = xrow + wv*(32*68);
    float* ms = msc + wv*(4*68);
    float rjx = r[3*j], rjy = r[3*j+1], rjz = r[3*j+2];
    float xres[8][4];
    {
      float4 w0 = *(const float4*)&W0[0*64 + 4*cg];
      float4 w1 = *(const float4*)&W0[1*64 + 4*cg];
      float4 w2 = *(const float4*)&W0[2*64 + 4*cg];
      float4 w3 = *(const float4*)&W0[3*64 + 4*cg];
      float4 bv = *(const float4*)&b0[4*cg];
      #pragma unroll
      for (int q = 0; q < 8; ++q) {
        int row = 4*q + rg;
        int i = i0 + row;
        float dx = rjx - r[3*i], dy = rjy - r[3*i+1], dz = rjz - r[3*i+2];
        float ee = (i == j) ? 1.f : 0.f;
        float ex = dx+ee, ey = dy+ee, ez = dz+ee;
        float len = sqrtf(ex*ex + ey*ey + ez*ez);
        float y0 = tanh_fast(bv.x + dx*w0.x + dy*w1.x + dz*w2.x + len*w3.x);
        float y1 = tanh_fast(bv.y + dx*w0.y + dy*w1.y + dz*w2.y + len*w3.y);
        float y2 = tanh_fast(bv.z + dx*w0.z + dy*w1.z + dz*w2.z + len*w3.z);
        float y3 = tanh_fast(bv.w + dx*w0.w + dy*w1.w + dz*w2.w + len*w3.w);
        xres[q][0]=y0; xres[q][1]=y1; xres[q][2]=y2; xres[q][3]=y3;
        float4 yv; yv.x=y0; yv.y=y1; yv.z=y2; yv.w=y3;
        *(float4*)&xr[row*68 + 4*cg] = yv;
      }
      float cs0=0,cs1=0,cs2=0,cs3=0;
      #pragma unroll
      for (int q=0;q<8;++q){cs0+=xres[q][0];cs1+=xres[q][1];cs2+=xres[q][2];cs3+=xres[q][3];}
      ms[rg*68+4*cg+0]=cs0; ms[rg*68+4*cg+1]=cs1;
      ms[rg*68+4*cg+2]=cs2; ms[rg*68+4*cg+3]=cs3;
      float tot = ms[0*68+lane]+ms[1*68+lane]+ms[2*68+lane]+ms[3*68+lane];
      g_part4[0*(16*NE*64) + chunk*(NE*64) + j*64 + lane] = tot;
    }
    for (int l = 0; l < 3; ++l) {
      __syncthreads();
      for (int idx = t; idx < 4096; idx += 256) wtile[idx] = Wr[l*4096 + idx];
      __syncthreads();
      float4 bv = *(const float4*)&brs[l*64 + 4*cg];
      float acc[8][4];
      #pragma unroll
      for (int q=0;q<8;++q){acc[q][0]=bv.x;acc[q][1]=bv.y;acc[q][2]=bv.z;acc[q][3]=bv.w;}
      #pragma unroll 4
      for (int kq = 0; kq < 16; ++kq) {
        float4 wv0 = *(const float4*)&wtile[(4*kq+0)*64 + 4*cg];
        float4 wv1 = *(const float4*)&wtile[(4*kq+1)*64 + 4*cg];
        float4 wv2 = *(const float4*)&wtile[(4*kq+2)*64 + 4*cg];
        float4 wv3 = *(const float4*)&wtile[(4*kq+3)*64 + 4*cg];
        #pragma unroll
        for (int q = 0; q < 8; ++q) {
          float4 xv = *(const float4*)&xr[(4*q+rg)*68 + 4*kq];
          acc[q][0] += xv.x*wv0.x + xv.y*wv1.x + xv.z*wv2.x + xv.w*wv3.x;
          acc[q][1] += xv.x*wv0.y + xv.y*wv1.y + xv.z*wv2.y + xv.w*wv3.y;
          acc[q][2] += xv.x*wv0.z + xv.y*wv1.z + xv.z*wv2.z + xv.w*wv3.z;
          acc[q][3] += xv.x*wv0.w + xv.y*wv1.w + xv.z*wv2.w + xv.w*wv3.w;
        }
      }
      float cs0=0,cs1=0,cs2=0,cs3=0;
      #pragma unroll
      for (int q = 0; q < 8; ++q) {
        float y0 = tanh_fast(acc[q][0]) + xres[q][0];
        float y1 = tanh_fast(acc[q][1]) + xres[q][1];
        float y2 = tanh_fast(acc[q][2]) + xres[q][2];
        float y3 = tanh_fast(acc[q][3]) + xres[q][3];
        xres[q][0]=y0; xres[q][1]=y1; xres[q][2]=y2; xres[q][3]=y3;
        float4 yv; yv.x=y0; yv.y=y1; yv.z=y2; yv.w=y3;
        *(float4*)&xr[(4*q+rg)*68 + 4*cg] = yv;
        cs0+=y0; cs1+=y1; cs2+=y2; cs3+=y3;
      }
      ms[rg*68+4*cg+0]=cs0; ms[rg*68+4*cg+1]=cs1;
      ms[rg*68+4*cg+2]=cs2; ms[rg*68+4*cg+3]=cs3;
      float tot = ms[0*68+lane]+ms[1*68+lane]+ms[2*68+lane]+ms[3*68+lane];
      g_part4[(l+1)*(16*NE*64) + chunk*(NE*64) + j*64 + lane] = tot;
    }
  }
}

// ---------------- s-channel matmul ----------------
// which: 0=layer0 (+ folded reduce_p), 1..3=layer l, 4=FUSED heads, 6=FUSED orbitals
// rsp: g_spart buffer to READ s-means from (-1 = use g_su0/g_sd0 or none)
// wsp: g_spart buffer to WRITE col partials to (-1 = none)
template<int PUK, int SVK, int MEANK>
__global__ __launch_bounds__(256) void k_smm(int which, const float* __restrict__ W,
                                             const float* __restrict__ Wb,
                                             const float* __restrict__ W2,
                                             const float* __restrict__ Wb2,
                                             int pl, int rsp, int wsp) {
  constexpr int MAINK = 2*PUK + SVK;
  __shared__ __align__(16) float wsl[MAINK*32];
  __shared__ float insl[32*(MAINK+1)];
  __shared__ float biasv[32];
  __shared__ float bred[256];
  __shared__ float susd[512];
  __shared__ float wred[4][8][4];
  const float *pu_p=nullptr, *pd_p=nullptr, *sv_p=nullptr, *su_p=nullptr, *sd_p=nullptr;
  const float *res_p=nullptr, *rs_p=nullptr;
  float* out_p = nullptr;
  int t = threadIdx.x;
  int rg = blockIdx.x, cg = blockIdx.y;
  // ---- folded reduce_p (smm0 dispatch only; independent of smm0's own work) ----
  if (which == 0) {
    int fid = blockIdx.y*16 + blockIdx.x;   // 0..127
    #pragma unroll
    for (int rep = 0; rep < 8; ++rep) {
      int idx = fid*2048 + rep*256 + t;     // covers 262144
      int l = idx >> 16;
      int rem = idx & 65535;
      int half = rem >> 15;
      int r2 = rem & 32767;
      const float* pp = g_part4 + l*(16*NE*64) + half*(8*NE*64) + r2;
      float s = 0.f;
      #pragma unroll
      for (int ch = 0; ch < 8; ++ch) s += pp[ch*(NE*64)];
      (half ? g_pdL : g_puL)[l*(NE*64) + r2] = s * (1.f/256.f);
    }
  }
  int grp = 0, rgl = rg;
  if (which >= 4) { grp = rg >> 3; rgl = rg & 7; }
  const float* Wsel = (which >= 4 && grp) ? W2 : W;
  const float* Wbsel = (which >= 4 && grp) ? Wb2 : Wb;
  int in_base = 0, dotanh = 1;
  switch (which) {
    case 0: pu_p=g_pu4; pd_p=g_pd4; su_p=g_su0; sd_p=g_sd0; sv_p=g_sv0;
            out_p=g_sv[0]; in_base=rg*32; break;
    case 1: case 2: case 3:
      pu_p=g_puL + pl*(NE*64); pd_p=g_pdL + pl*(NE*64);
      sv_p=g_sv[(which+1)&1]; res_p=sv_p; out_p=g_sv[which&1]; in_base=rg*32; break;
    case 4: pu_p=g_puL + pl*(NE*64); pd_p=g_pdL + pl*(NE*64);
            sv_p=g_sv[1]; out_p = grp ? g_hd : g_hu; in_base = grp*256 + rgl*32; break;
    default: sv_p = grp ? g_hd : g_hu; out_p = grp ? g_orbd : g_orbu;
             rs_p = g_f + grp*256; in_base = rgl*32; dotanh = 0; break;
  }
  // rebuild s-means from producer's col partials (replaces the smean dispatch)
  if (rsp >= 0 && MEANK == 256) {
    const float* sp = g_spart[rsp];
    for (int e = t; e < 512; e += 256) {
      int half = e >> 8, c = e & 255;
      float s = 0.f;
      #pragma unroll
      for (int g8 = 0; g8 < 8; ++g8) s += sp[(half*8 + g8)*256 + c];
      susd[e] = s * (1.f/256.f);
    }
    su_p = &susd[0]; sd_p = &susd[256];
    __syncthreads();
  }
  int out_base = (which >= 4) ? rgl*32 : rg*32;
  int col0 = cg * 32;
  for (int idx = t; idx < MAINK*32; idx += 256) {
    int c = idx >> 5, cl = idx & 31;
    wsl[idx] = Wsel[(2*MEANK + c)*256 + col0 + cl];
  }
  for (int rr = 0; rr < 32; ++rr) {
    int row = in_base + rr;
    for (int c = t; c < MAINK; c += 256) {
      float v;
      if (c < PUK) v = pu_p[row*PUK + c];
      else if (c < 2*PUK) v = pd_p[row*PUK + (c - PUK)];
      else v = sv_p[row*SVK + (c - 2*PUK)];
      insl[rr*(MAINK+1) + c] = v;
    }
  }
  {
    int pcol = t & 31, ps = t >> 5;
    float bacc = 0.f;
    if (MEANK > 0) {
      for (int c = ps; c < MEANK; c += 8)
        bacc += su_p[c]*Wsel[c*256 + col0 + pcol] + sd_p[c]*Wsel[(MEANK + c)*256 + col0 + pcol];
    }
    bred[ps*32 + pcol] = bacc;
  }
  __syncthreads();
  if (t < 32) {
    float s = Wbsel[col0 + t];
    #pragma unroll
    for (int p8 = 0; p8 < 8; ++p8) s += bred[p8*32 + t];
    biasv[t] = s;
  }
  __syncthreads();
  int c4 = t & 7, rl = t >> 3;
  float a0 = biasv[4*c4], a1 = biasv[4*c4+1], a2 = biasv[4*c4+2], a3 = biasv[4*c4+3];
  const float* inrow = &insl[rl*(MAINK+1)];
  #pragma unroll 4
  for (int c = 0; c < MAINK; ++c) {
    float iv = inrow[c];
    float4 wv = *(const float4*)&wsl[c*32 + 4*c4];
    a0 += iv*wv.x; a1 += iv*wv.y; a2 += iv*wv.z; a3 += iv*wv.w;
  }
  int rowA = out_base + rl;
  int col = col0 + 4*c4;
  if (dotanh) { a0=tanh_fast(a0); a1=tanh_fast(a1); a2=tanh_fast(a2); a3=tanh_fast(a3); }
  if (res_p) {
    float4 rv = *(const float4*)&res_p[rowA*256 + col];
    a0 += rv.x; a1 += rv.y; a2 += rv.z; a3 += rv.w;
  }
  if (rs_p) { float fsc = rs_p[rowA]; a0*=fsc; a1*=fsc; a2*=fsc; a3*=fsc; }
  float4 ov; ov.x=a0; ov.y=a1; ov.z=a2; ov.w=a3;
  *(float4*)&out_p[rowA*256 + col] = ov;
  // ---- col partials for the NEXT layer's s-means ----
  if (wsp >= 0) {
    int lane = t & 63, wv = t >> 6;
    float s0=a0, s1=a1, s2=a2, s3=a3;
    #pragma unroll
    for (int m = 8; m < 64; m <<= 1) {
      s0 += __shfl_xor(s0, m); s1 += __shfl_xor(s1, m);
      s2 += __shfl_xor(s2, m); s3 += __shfl_xor(s3, m);
    }
    if ((lane >> 3) == 0) {
      wred[wv][c4][0]=s0; wred[wv][c4][1]=s1; wred[wv][c4][2]=s2; wred[wv][c4][3]=s3;
    }
    __syncthreads();
    if (t < 32) {
      int cc4 = t >> 2, cc = t & 3;
      float tot = wred[0][cc4][cc]+wred[1][cc4][cc]+wred[2][cc4][cc]+wred[3][cc4][cc];
      g_spart[wsp][rg*256 + col0 + 4*cc4 + cc] = tot;
    }
  }
}

// ---------------- register-resident LU, v8 (best measured: 249-253us) ----------------
// R18 lesson: owner-register search (v9 bundled, v10 unbundled) BOTH regress with the
// same 261K bank-conflict signature — concentrating search+extract+scal posts in one
// half-wave serializes the region. v8's redundant all-thread search overlaps better.
// This is the LU floor for this algorithm at HIP level (~2300 cyc/col).
#define REP8(M) M(0) M(1) M(2) M(3) M(4) M(5) M(6) M(7)
#define DPPMAX(v, CTRL) { unsigned _o = (unsigned)__builtin_amdgcn_update_dpp(0, (int)(v), CTRL, 0xf, 0xf, true); \
                          (v) = (v) > _o ? (v) : _o; }

__global__ __launch_bounds__(512, 2) void k_lu(float* __restrict__ out) {
  __shared__ __align__(16) float colbuf[2][256];
  __shared__ __align__(16) float prowbuf[2][16*20];
  const float* A = (blockIdx.x == 0) ? g_orbu : g_orbd;
  int t = threadIdx.x;
  int tile_c = t >> 5;        // 0..15 -> cols 16*tile_c .. +15
  int tile_r = t & 31;        // 0..31 -> rows 8*tile_r .. +7
  int lane = t & 63;
  int br = tile_r * 8;
  int pb = tile_c * 20;
  const float4* Ap = (const float4*)(A + br*256 + tile_c*16);
#define DECLROW(R) float4 M##R##_0 = Ap[R*64+0], M##R##_1 = Ap[R*64+1], \
                          M##R##_2 = Ap[R*64+2], M##R##_3 = Ap[R*64+3];
  REP8(DECLROW)
#undef DECLROW
  unsigned um = 0;
  if (tile_c == 0) {
#define INIT0(R) colbuf[0][br+R] = M##R##_0.x;
    REP8(INIT0)
#undef INIT0
  }
  __syncthreads();
  float prod = 1.f;
  int esum = 0;
  float m0=0,m1=0,m2=0,m3=0,m4=0,m5=0,m6=0,m7=0;
  for (int k = 0; k < 256; ++k) {
    const float* cbin = colbuf[k & 1];
    float4 cv = *(const float4*)&cbin[4*lane];
    float4 ca = *(const float4*)&cbin[br];
    float4 cb2 = *(const float4*)&cbin[br+4];
    bool aliveU = (tile_c*16 + 15) >= k;
    if (k > 0 && aliveU) {
      const float* pwp = &prowbuf[(k-1) & 1][pb];
      float4 P0 = *(const float4*)&pwp[0];
      float4 P1 = *(const float4*)&pwp[4];
      float4 P2 = *(const float4*)&pwp[8];
      float4 P3 = *(const float4*)&pwp[12];
#define UPD(R) { float mr = m##R; \
  M##R##_0.x -= mr*P0.x; M##R##_0.y -= mr*P0.y; M##R##_0.z -= mr*P0.z; M##R##_0.w -= mr*P0.w; \
  M##R##_1.x -= mr*P1.x; M##R##_1.y -= mr*P1.y; M##R##_1.z -= mr*P1.z; M##R##_1.w -= mr*P1.w; \
  M##R##_2.x -= mr*P2.x; M##R##_2.y -= mr*P2.y; M##R##_2.z -= mr*P2.z; M##R##_2.w -= mr*P2.w; \
  M##R##_3.x -= mr*P3.x; M##R##_3.y -= mr*P3.y; M##R##_3.z -= mr*P3.z; M##R##_3.w -= mr*P3.w; }
      REP8(UPD)
#undef UPD
    }
    unsigned b0 = (um & 1u) ? 0u : ((__float_as_uint(fabsf(cv.x)) & 0xFFFFFF00u) | (unsigned)(4*lane+0));
    unsigned b1 = (um & 2u) ? 0u : ((__float_as_uint(fabsf(cv.y)) & 0xFFFFFF00u) | (unsigned)(4*lane+1));
    unsigned b2 = (um & 4u) ? 0u : ((__float_as_uint(fabsf(cv.z)) & 0xFFFFFF00u) | (unsigned)(4*lane+2));
    unsigned b3 = (um & 8u) ? 0u : ((__float_as_uint(fabsf(cv.w)) & 0xFFFFFF00u) | (unsigned)(4*lane+3));
    unsigned bb = max(max(b0,b1), max(b2,b3));
    DPPMAX(bb, 0x111) DPPMAX(bb, 0x112) DPPMAX(bb, 0x114) DPPMAX(bb, 0x118)
    DPPMAX(bb, 0x142) DPPMAX(bb, 0x143)
    bb = (unsigned)__builtin_amdgcn_readlane((int)bb, 63);
    int p = (int)(bb & 255u);
    int wl = p >> 2, cc = p & 3;
    unsigned px = (unsigned)__builtin_amdgcn_readlane((int)__float_as_uint(cv.x), wl);
    unsigned py = (unsigned)__builtin_amdgcn_readlane((int)__float_as_uint(cv.y), wl);
    unsigned pz = (unsigned)__builtin_amdgcn_readlane((int)__float_as_uint(cv.z), wl);
    unsigned pw = (unsigned)__builtin_amdgcn_readlane((int)__float_as_uint(cv.w), wl);
    float piv = __uint_as_float(cc==0 ? px : cc==1 ? py : cc==2 ? pz : pw);
    int ee; float mant = frexpf(fabsf(piv), &ee);
    prod *= mant; esum += ee;
    int e2; prod = frexpf(prod, &e2); esum += e2;   // keep prod in [0.25,1)
    if (wl == lane) um |= 1u << cc;
    if (k == 255) break;
    float rp = 1.0f / piv;
    m0 = ca.x*rp; m1 = ca.y*rp; m2 = ca.z*rp; m3 = ca.w*rp;
    m4 = cb2.x*rp; m5 = cb2.y*rp; m6 = cb2.z*rp; m7 = cb2.w*rp;
    bool aliveK = (tile_c*16 + 15) > k;
    if (aliveK && tile_r == (p >> 3)) {
      float* pw_ = &prowbuf[k & 1][pb];
      switch (p & 7) {
#define PUBC(R) case R: *(float4*)&pw_[0] = M##R##_0; *(float4*)&pw_[4] = M##R##_1; \
                        *(float4*)&pw_[8] = M##R##_2; *(float4*)&pw_[12] = M##R##_3; break;
        REP8(PUBC)
#undef PUBC
      }
    }
    int kn = k + 1;
    if (tile_c == (kn >> 4)) {
      float e0,e1,e2b,e3,e4,e5,e6,e7;
      switch (kn & 15) {
#define EXTC(I, G, C) case I: e0=M0_##G.C; e1=M1_##G.C; e2b=M2_##G.C; e3=M3_##G.C; \
                              e4=M4_##G.C; e5=M5_##G.C; e6=M6_##G.C; e7=M7_##G.C; break;
        EXTC(0,0,x) EXTC(1,0,y) EXTC(2,0,z) EXTC(3,0,w)
        EXTC(4,1,x) EXTC(5,1,y) EXTC(6,1,z) EXTC(7,1,w)
        EXTC(8,2,x) EXTC(9,2,y) EXTC(10,2,z) EXTC(11,2,w)
        EXTC(12,3,x) EXTC(13,3,y) EXTC(14,3,z) EXTC(15,3,w)
#undef EXTC
      }
      float sel;
      switch (p & 7) {
        case 0: sel = e0; break; case 1: sel = e1; break;
        case 2: sel = e2b; break; case 3: sel = e3; break;
        case 4: sel = e4; break; case 5: sel = e5; break;
        case 6: sel = e6; break; default: sel = e7; break;
      }
      float pv = __shfl(sel, (tile_c & 1)*32 + (p >> 3), 64);
      float4 w0, w1;
      w0.x = e0 - m0*pv; w0.y = e1 - m1*pv; w0.z = e2b - m2*pv; w0.w = e3 - m3*pv;
      w1.x = e4 - m4*pv; w1.y = e5 - m5*pv; w1.z = e6 - m6*pv; w1.w = e7 - m7*pv;
      *(float4*)&colbuf[kn & 1][br] = w0;
      *(float4*)&colbuf[kn & 1][br+4] = w1;
    }
    __syncthreads();
  }
  if (t == 0) {
    float ls = logf(prod) + (float)esum * 0.69314718055994531f;
    __hip_atomic_store(&g_logs[blockIdx.x], ls, __ATOMIC_RELEASE, __HIP_MEMORY_SCOPE_AGENT);
    unsigned old = __hip_atomic_fetch_add(&g_ludone, 1u, __ATOMIC_ACQ_REL, __HIP_MEMORY_SCOPE_AGENT);
    if (old == 1u) {   // second finisher writes the final scalar
      float l0 = __hip_atomic_load(&g_logs[0], __ATOMIC_ACQUIRE, __HIP_MEMORY_SCOPE_AGENT);
      float l1 = __hip_atomic_load(&g_logs[1], __ATOMIC_ACQUIRE, __HIP_MEMORY_SCOPE_AGENT);
      out[0] = l0 + l1;
    }
  }
}

// ---------------- launch (8 dispatches) ----------------
extern "C" void kernel_launch(void* const* d_in, const int* in_sizes, int n_in,
                              void* d_out, int out_size, void* d_ws, size_t ws_size,
                              hipStream_t stream) {
  const float* r     = (const float*)d_in[0];
  const float* a     = (const float*)d_in[1];
  const float* V0_W  = (const float*)d_in[2];
  const float* V0_b  = (const float*)d_in[3];
  const float* Vr_W  = (const float*)d_in[4];
  const float* Vr_b  = (const float*)d_in[5];
  const float* W0_W  = (const float*)d_in[6];
  const float* W0_b  = (const float*)d_in[7];
  const float* Wr_W  = (const float*)d_in[8];
  const float* Wr_b  = (const float*)d_in[9];
  const float* Vhu_W = (const float*)d_in[10];
  const float* Vhu_b = (const float*)d_in[11];
  const float* Vhd_W = (const float*)d_in[12];
  const float* Vhd_b = (const float*)d_in[13];
  const float* wu_W  = (const float*)d_in[14];
  const float* wu_b  = (const float*)d_in[15];
  const float* wd_W  = (const float*)d_in[16];
  const float* wd_b  = (const float*)d_in[17];
  float* out = (float*)d_out;

  k_front<<<2560, 256, 0, stream>>>(r, a, W0_W, W0_b, Wr_W, Wr_b);
  // smm0 carries the folded reduce_p
  k_smm<4,64,64><<<dim3(16,8), 256, 0, stream>>>(0, V0_W, V0_b, nullptr, nullptr,
                                                 0, -1, 0);
  k_smm<64,256,256><<<dim3(16,8), 256, 0, stream>>>(1, Vr_W + 0*896*256, Vr_b + 0,
                                                    nullptr, nullptr, 0, 0, 1);
  k_smm<64,256,256><<<dim3(16,8), 256, 0, stream>>>(2, Vr_W + 1*896*256, Vr_b + 256,
                                                    nullptr, nullptr, 1, 1, 0);
  k_smm<64,256,256><<<dim3(16,8), 256, 0, stream>>>(3, Vr_W + 2*896*256, Vr_b + 512,
                                                    nullptr, nullptr, 2, 0, 1);
  k_smm<64,256,256><<<dim3(16,8), 256, 0, stream>>>(4, Vhu_W, Vhu_b, Vhd_W, Vhd_b,
                                                    3, 1, -1);
  k_smm<0,256,0><<<dim3(16,8), 256, 0, stream>>>(6, wu_W, wu_b, wd_W, wd_b,
                                                 0, -1, -1);
  k_lu<<<2, 512, 0, stream>>>(out);
}